// Round 1
// baseline (564.971 us; speedup 1.0000x reference)
//
#include <hip/hip_runtime.h>

typedef unsigned short u16;
typedef __attribute__((ext_vector_type(8))) short s16x8;
typedef __attribute__((ext_vector_type(4))) float f32x4;

#define MFMA16(a,b,c) __builtin_amdgcn_mfma_f32_16x16x32_bf16((a),(b),(c),0,0,0)

#define LSEQ 2048

__device__ __forceinline__ u16 f2b(float f) {
  union { float f; unsigned u; } v; v.f = f;
  unsigned r = v.u + 0x7FFFu + ((v.u >> 16) & 1u);
  return (u16)(r >> 16);
}

// ---------------- convert f32 -> bf16, 4 elems/thread ----------------
__global__ __launch_bounds__(256) void k_cvt(const float* __restrict__ in, u16* __restrict__ out, int n) {
  int i = (blockIdx.x * 256 + threadIdx.x) * 4;
  if (i + 3 < n) {
    float4 v = *(const float4*)(in + i);
    ushort4 o;
    o.x = f2b(v.x); o.y = f2b(v.y); o.z = f2b(v.z); o.w = f2b(v.w);
    *(ushort4*)(out + i) = o;
  }
}

// ------------- transpose+convert: W[K,N] f32 -> Wt[N,K] bf16 -------------
__global__ __launch_bounds__(256) void k_transpose(const float* __restrict__ W, u16* __restrict__ Wt, int K, int N) {
  __shared__ float T[64][65];
  int k0 = blockIdx.y * 64, n0 = blockIdx.x * 64;
  int r = threadIdx.x >> 4;          // 0..15
  int c4 = (threadIdx.x & 15) * 4;   // 0..60
#pragma unroll
  for (int i = 0; i < 4; i++) {
    float4 v = *(const float4*)(W + (size_t)(k0 + r + i * 16) * N + n0 + c4);
    T[r + i * 16][c4 + 0] = v.x; T[r + i * 16][c4 + 1] = v.y;
    T[r + i * 16][c4 + 2] = v.z; T[r + i * 16][c4 + 3] = v.w;
  }
  __syncthreads();
#pragma unroll
  for (int i = 0; i < 4; i++) {
    int nl = r + i * 16;
    ushort4 o;
    o.x = f2b(T[c4 + 0][nl]); o.y = f2b(T[c4 + 1][nl]);
    o.z = f2b(T[c4 + 2][nl]); o.w = f2b(T[c4 + 3][nl]);
    *(ushort4*)(Wt + (size_t)(n0 + nl) * K + k0 + c4) = o;
  }
}

// ------------- generic bf16 MFMA GEMM: C[M,N] = A[M,K] @ Bt[N,K]^T + bias -------------
// FLAGS: 1=RELU, 2=BF16OUT, 4=HEADMAJOR(bf16), 8=RESID(f32)
template <int FLAGS>
__global__ __launch_bounds__(256) void k_gemm(const u16* __restrict__ A, const u16* __restrict__ Bt,
                                              const float* __restrict__ bias, const float* __restrict__ resid,
                                              void* __restrict__ Cout, int M, int N, int K, float scale) {
  __shared__ __align__(16) u16 As[128][40];
  __shared__ __align__(16) u16 Bs[128][40];
  const int tid = threadIdx.x;
  const int lane = tid & 63, wave = tid >> 6;
  const int lo = lane & 15, hi = lane >> 4;
  const int wr = wave >> 1, wc = wave & 1;
  const int m0 = blockIdx.y * 128, n0 = blockIdx.x * 128;

  f32x4 acc[4][4];
#pragma unroll
  for (int i = 0; i < 4; i++)
#pragma unroll
    for (int j = 0; j < 4; j++) acc[i][j] = (f32x4){0.f, 0.f, 0.f, 0.f};

  const int sr = tid >> 1, scc = (tid & 1) * 16;
  for (int k0 = 0; k0 < K; k0 += 32) {
    __syncthreads();
    const u16* srcA = A + (size_t)(m0 + sr) * K + k0 + scc;
    *(uint4*)&As[sr][scc]     = *(const uint4*)srcA;
    *(uint4*)&As[sr][scc + 8] = *(const uint4*)(srcA + 8);
    const u16* srcB = Bt + (size_t)(n0 + sr) * K + k0 + scc;
    *(uint4*)&Bs[sr][scc]     = *(const uint4*)srcB;
    *(uint4*)&Bs[sr][scc + 8] = *(const uint4*)(srcB + 8);
    __syncthreads();
    s16x8 af[4], bfr[4];
#pragma unroll
    for (int mi = 0; mi < 4; mi++) af[mi] = *(const s16x8*)&As[wr * 64 + mi * 16 + lo][hi * 8];
#pragma unroll
    for (int ni = 0; ni < 4; ni++) bfr[ni] = *(const s16x8*)&Bs[wc * 64 + ni * 16 + lo][hi * 8];
#pragma unroll
    for (int mi = 0; mi < 4; mi++)
#pragma unroll
      for (int ni = 0; ni < 4; ni++)
        acc[mi][ni] = MFMA16(af[mi], bfr[ni], acc[mi][ni]);
  }

#pragma unroll
  for (int mi = 0; mi < 4; mi++)
#pragma unroll
    for (int ni = 0; ni < 4; ni++)
#pragma unroll
      for (int reg = 0; reg < 4; reg++) {
        int m = m0 + wr * 64 + mi * 16 + hi * 4 + reg;
        int n = n0 + wc * 64 + ni * 16 + lo;
        float v = acc[mi][ni][reg] + bias[n];
        if (FLAGS & 8) v += resid[(size_t)m * N + n];
        if (FLAGS & 1) v = fmaxf(v, 0.f);
        v *= scale;
        if (FLAGS & 4) {
          int bb = m >> 11, l = m & 2047, hh = n >> 6, dd = n & 63;
          ((u16*)Cout)[((size_t)(bb * 16 + hh) * LSEQ + l) * 64 + dd] = f2b(v);
        } else if (FLAGS & 2) {
          ((u16*)Cout)[(size_t)m * N + n] = f2b(v);
        } else {
          ((float*)Cout)[(size_t)m * N + n] = v;
        }
      }
}

// ------------- fused rel-pos flash attention -------------
// Q pre-scaled by 1/8. Layouts: Qh/Kh/Vh = [B*H, L, 64] bf16. Ob = [B*L, 1024] bf16.
// grid (L/64, B*H), block 256. Wave w handles query rows [l0+16w, l0+16w+16).
__global__ __launch_bounds__(256) void k_attn(const u16* __restrict__ Qh, const u16* __restrict__ Kh,
                                              const u16* __restrict__ Vh, const u16* __restrict__ Eb,
                                              u16* __restrict__ Ob) {
  __shared__ __align__(16) u16 Ksh[64][80];     // [j][dh]
  __shared__ __align__(16) u16 Vts[64][80];     // [dh][j]
  __shared__ __align__(16) u16 Esh[128][80];    // [m-mbB][dh]
  __shared__ __align__(16) u16 Psh[4][16][80];  // per-wave [r][j]
  __shared__ float Gsh[4][16][80];              // per-wave [r][mm]

  const int tid = threadIdx.x;
  const int lane = tid & 63, wave = tid >> 6;
  const int lo = lane & 15, hi = lane >> 4;
  const int l0 = blockIdx.x * 64;
  const int bh = blockIdx.y;
  const int bb = bh >> 4, hh = bh & 15;
  const int lw = l0 + wave * 16;

  const u16* Qbase = Qh + (size_t)bh * LSEQ * 64;
  const u16* Kbase = Kh + (size_t)bh * LSEQ * 64;
  const u16* Vbase = Vh + (size_t)bh * LSEQ * 64;

  s16x8 aq[2];
  aq[0] = *(const s16x8*)(Qbase + (size_t)(lw + lo) * 64 + hi * 8);
  aq[1] = *(const s16x8*)(Qbase + (size_t)(lw + lo) * 64 + 32 + hi * 8);

  float m_run[4], l_run[4];
  f32x4 oacc[4];
#pragma unroll
  for (int r = 0; r < 4; r++) { m_run[r] = -1e30f; l_run[r] = 0.f; }
#pragma unroll
  for (int f = 0; f < 4; f++) oacc[f] = (f32x4){0.f, 0.f, 0.f, 0.f};

  const int str = tid >> 2;          // 0..63
  const int stc = (tid & 3) * 16;    // 0,16,32,48
  const int er = tid >> 1;           // 0..127
  const int ec = (tid & 1) * 32;

  for (int j0 = 0; j0 < LSEQ; j0 += 64) {
    const bool has_rel = (j0 <= l0);
    __syncthreads();
    {  // stage K tile [j][dh]
      const u16* s = Kbase + (size_t)(j0 + str) * 64 + stc;
      *(uint4*)&Ksh[str][stc]     = *(const uint4*)s;
      *(uint4*)&Ksh[str][stc + 8] = *(const uint4*)(s + 8);
    }
    {  // stage V transposed [dh][j]
      const u16* s = Vbase + (size_t)(j0 + str) * 64 + stc;
      u16 tmp[16];
      *(uint4*)&tmp[0] = *(const uint4*)s;
      *(uint4*)&tmp[8] = *(const uint4*)(s + 8);
#pragma unroll
      for (int i = 0; i < 16; i++) Vts[stc + i][str] = tmp[i];
    }
    if (has_rel) {  // stage E band rows [mbB, mbB+128)
      const int mbB = LSEQ - 64 - l0 + j0;
      int mrow = mbB + er;
      if (mrow < LSEQ) {
        const u16* s = Eb + (size_t)mrow * 64 + ec;
#pragma unroll
        for (int i = 0; i < 4; i++) *(uint4*)&Esh[er][ec + i * 8] = *(const uint4*)(s + i * 8);
      } else {
        uint4 z = {0u, 0u, 0u, 0u};
#pragma unroll
        for (int i = 0; i < 4; i++) *(uint4*)&Esh[er][ec + i * 8] = z;
      }
    }
    __syncthreads();

    // S = Q K^T  (scaled via pre-scaled Q)
    f32x4 s4[4];
#pragma unroll
    for (int c = 0; c < 4; c++) {
      s4[c] = (f32x4){0.f, 0.f, 0.f, 0.f};
      s16x8 b0 = *(const s16x8*)&Ksh[c * 16 + lo][hi * 8];
      s16x8 b1 = *(const s16x8*)&Ksh[c * 16 + lo][32 + hi * 8];
      s4[c] = MFMA16(aq[0], b0, s4[c]);
      s4[c] = MFMA16(aq[1], b1, s4[c]);
    }

    if (has_rel) {
      const int offW = 48 - 16 * wave;  // wave band start within block band
#pragma unroll
      for (int c2 = 0; c2 < 5; c2++) {
        f32x4 g = (f32x4){0.f, 0.f, 0.f, 0.f};
        s16x8 e0 = *(const s16x8*)&Esh[offW + c2 * 16 + lo][hi * 8];
        s16x8 e1 = *(const s16x8*)&Esh[offW + c2 * 16 + lo][32 + hi * 8];
        g = MFMA16(aq[0], e0, g);
        g = MFMA16(aq[1], e1, g);
#pragma unroll
        for (int reg = 0; reg < 4; reg++) Gsh[wave][hi * 4 + reg][c2 * 16 + lo] = g[reg];
      }
      // srel gather: rel[l,j] = (j<=l) ? G[r][15 - r + (j-j0-) ...] : 0
#pragma unroll
      for (int c = 0; c < 4; c++)
#pragma unroll
        for (int reg = 0; reg < 4; reg++) {
          int r = hi * 4 + reg;
          int jg = j0 + c * 16 + lo;
          int lg = lw + r;
          if (jg <= lg) {
            int mm = 15 - r + c * 16 + lo;
            s4[c][reg] += Gsh[wave][r][mm];
          }
        }
    }

    // online softmax (rows r = hi*4+reg, cols across the 16-lane lo group x 4 frags)
    float mt[4];
#pragma unroll
    for (int reg = 0; reg < 4; reg++)
      mt[reg] = fmaxf(fmaxf(s4[0][reg], s4[1][reg]), fmaxf(s4[2][reg], s4[3][reg]));
#pragma unroll
    for (int msk = 1; msk <= 8; msk <<= 1)
#pragma unroll
      for (int reg = 0; reg < 4; reg++)
        mt[reg] = fmaxf(mt[reg], __shfl_xor(mt[reg], msk, 64));
    float psum[4];
#pragma unroll
    for (int reg = 0; reg < 4; reg++) {
      float mnew = fmaxf(m_run[reg], mt[reg]);
      float scl = __expf(m_run[reg] - mnew);
      m_run[reg] = mnew;
      l_run[reg] *= scl;
#pragma unroll
      for (int f = 0; f < 4; f++) oacc[f][reg] *= scl;
      psum[reg] = 0.f;
    }
#pragma unroll
    for (int c = 0; c < 4; c++)
#pragma unroll
      for (int reg = 0; reg < 4; reg++) {
        float p = __expf(s4[c][reg] - m_run[reg]);
        psum[reg] += p;
        Psh[wave][hi * 4 + reg][c * 16 + lo] = f2b(p);
      }
#pragma unroll
    for (int msk = 1; msk <= 8; msk <<= 1)
#pragma unroll
      for (int reg = 0; reg < 4; reg++)
        psum[reg] += __shfl_xor(psum[reg], msk, 64);
#pragma unroll
    for (int reg = 0; reg < 4; reg++) l_run[reg] += psum[reg];

    // O += P V
    s16x8 pa0 = *(const s16x8*)&Psh[wave][lo][hi * 8];
    s16x8 pa1 = *(const s16x8*)&Psh[wave][lo][32 + hi * 8];
#pragma unroll
    for (int f = 0; f < 4; f++) {
      s16x8 v0 = *(const s16x8*)&Vts[f * 16 + lo][hi * 8];
      s16x8 v1 = *(const s16x8*)&Vts[f * 16 + lo][32 + hi * 8];
      oacc[f] = MFMA16(pa0, v0, oacc[f]);
      oacc[f] = MFMA16(pa1, v1, oacc[f]);
    }
  }

  float inv[4];
#pragma unroll
  for (int reg = 0; reg < 4; reg++) inv[reg] = 1.f / l_run[reg];
#pragma unroll
  for (int f = 0; f < 4; f++)
#pragma unroll
    for (int reg = 0; reg < 4; reg++) {
      float o = oacc[f][reg] * inv[reg];
      size_t idx = (size_t)(bb * LSEQ + lw + hi * 4 + reg) * 1024 + hh * 64 + f * 16 + lo;
      Ob[idx] = f2b(o);
    }
}

// ------------- LayerNorm over rows of 1024, optional bf16 copy, in-place safe -------------
__global__ __launch_bounds__(256) void k_layernorm(const float* __restrict__ X, const float* __restrict__ gw,
                                                   const float* __restrict__ bw, float* __restrict__ outF,
                                                   u16* __restrict__ outB) {
  __shared__ float red[2][4];
  const int row = blockIdx.x, tid = threadIdx.x;
  const int lane = tid & 63, wave = tid >> 6;
  const float* x = X + (size_t)row * 1024;
  float4 v = *(const float4*)(x + tid * 4);
  float s = v.x + v.y + v.z + v.w;
  float s2 = v.x * v.x + v.y * v.y + v.z * v.z + v.w * v.w;
#pragma unroll
  for (int msk = 1; msk <= 32; msk <<= 1) {
    s += __shfl_xor(s, msk, 64);
    s2 += __shfl_xor(s2, msk, 64);
  }
  if (lane == 0) { red[0][wave] = s; red[1][wave] = s2; }
  __syncthreads();
  s = red[0][0] + red[0][1] + red[0][2] + red[0][3];
  s2 = red[1][0] + red[1][1] + red[1][2] + red[1][3];
  float mean = s * (1.f / 1024.f);
  float var = s2 * (1.f / 1024.f) - mean * mean;
  float rs = rsqrtf(var + 1e-6f);
  float4 g4 = *(const float4*)(gw + tid * 4);
  float4 b4 = *(const float4*)(bw + tid * 4);
  float4 o;
  o.x = (v.x - mean) * rs * g4.x + b4.x;
  o.y = (v.y - mean) * rs * g4.y + b4.y;
  o.z = (v.z - mean) * rs * g4.z + b4.z;
  o.w = (v.w - mean) * rs * g4.w + b4.w;
  *(float4*)(outF + (size_t)row * 1024 + tid * 4) = o;
  if (outB) {
    ushort4 ob;
    ob.x = f2b(o.x); ob.y = f2b(o.y); ob.z = f2b(o.z); ob.w = f2b(o.w);
    *(ushort4*)(outB + (size_t)row * 1024 + tid * 4) = ob;
  }
}

extern "C" void kernel_launch(void* const* d_in, const int* in_sizes, int n_in,
                              void* d_out, int out_size, void* d_ws, size_t ws_size,
                              hipStream_t stream) {
  const float* x   = (const float*)d_in[0];
  const float* Wq  = (const float*)d_in[1];
  const float* bq  = (const float*)d_in[2];
  const float* Wk  = (const float*)d_in[3];
  const float* bk  = (const float*)d_in[4];
  const float* Wv  = (const float*)d_in[5];
  const float* bv  = (const float*)d_in[6];
  const float* Wo  = (const float*)d_in[7];
  const float* bo  = (const float*)d_in[8];
  const float* E   = (const float*)d_in[9];
  const float* W1  = (const float*)d_in[10];
  const float* b1  = (const float*)d_in[11];
  const float* W2  = (const float*)d_in[12];
  const float* b2  = (const float*)d_in[13];
  const float* g1  = (const float*)d_in[14];
  const float* be1 = (const float*)d_in[15];
  const float* g2  = (const float*)d_in[16];
  const float* be2 = (const float*)d_in[17];

  char* ws = (char*)d_ws;
  const size_t MB = 1ull << 20;
  u16* Wqt = (u16*)(ws + 0 * MB);    // 2MB  [1024][1024]
  u16* Wkt = (u16*)(ws + 2 * MB);    // 2MB
  u16* Wvt = (u16*)(ws + 4 * MB);    // 2MB
  u16* Wot = (u16*)(ws + 6 * MB);    // 2MB
  u16* W1t = (u16*)(ws + 8 * MB);    // 8MB  [4096][1024]
  u16* W2t = (u16*)(ws + 16 * MB);   // 8MB  [1024][4096]
  u16* Ebf = (u16*)(ws + 24 * MB);   // 256KB [2048][64]
  u16* xb  = (u16*)(ws + 25 * MB);   // 8MB  [4096][1024]
  u16* qb  = (u16*)(ws + 33 * MB);   // 8MB  head-major
  u16* kb  = (u16*)(ws + 41 * MB);   // 8MB
  u16* vb  = (u16*)(ws + 49 * MB);   // 8MB
  u16* ao  = (u16*)(ws + 57 * MB);   // 8MB  [4096][1024] bf16
  float* t1 = (float*)(ws + 65 * MB);  // 16MB f32
  u16* o1b  = (u16*)(ws + 25 * MB);  // reuse xb (dead after QKV)
  float* o1f = (float*)(ws + 33 * MB); // reuse q/k (dead after attn), 16MB
  u16* h1b  = (u16*)(ws + 49 * MB);  // reuse v/ao/t1, 32MB [4096][4096]
  float* outF = (float*)d_out;

  // 1) dtype conversions
  k_cvt<<<4096, 256, 0, stream>>>(x, xb, 4096 * 1024);
  k_cvt<<<128, 256, 0, stream>>>(E, Ebf, 2048 * 64);
  k_transpose<<<dim3(16, 16), 256, 0, stream>>>(Wq, Wqt, 1024, 1024);
  k_transpose<<<dim3(16, 16), 256, 0, stream>>>(Wk, Wkt, 1024, 1024);
  k_transpose<<<dim3(16, 16), 256, 0, stream>>>(Wv, Wvt, 1024, 1024);
  k_transpose<<<dim3(16, 16), 256, 0, stream>>>(Wo, Wot, 1024, 1024);
  k_transpose<<<dim3(64, 16), 256, 0, stream>>>(W1, W1t, 1024, 4096);
  k_transpose<<<dim3(16, 64), 256, 0, stream>>>(W2, W2t, 4096, 1024);

  // 2) QKV projections (head-major bf16; Q pre-scaled by 1/sqrt(DH)=1/8)
  k_gemm<4><<<dim3(8, 32), 256, 0, stream>>>(xb, Wqt, bq, nullptr, qb, 4096, 1024, 1024, 0.125f);
  k_gemm<4><<<dim3(8, 32), 256, 0, stream>>>(xb, Wkt, bk, nullptr, kb, 4096, 1024, 1024, 1.f);
  k_gemm<4><<<dim3(8, 32), 256, 0, stream>>>(xb, Wvt, bv, nullptr, vb, 4096, 1024, 1024, 1.f);

  // 3) rel-pos flash attention -> ao [B*L, D] bf16
  k_attn<<<dim3(32, 32), 256, 0, stream>>>(qb, kb, vb, Ebf, ao);

  // 4) O-proj + residual(x) -> t1 f32
  k_gemm<8><<<dim3(8, 32), 256, 0, stream>>>(ao, Wot, bo, x, t1, 4096, 1024, 1024, 1.f);

  // 5) LN1 -> out1 (f32 + bf16)
  k_layernorm<<<4096, 256, 0, stream>>>(t1, g1, be1, o1f, o1b);

  // 6) FFN1: relu(out1 @ W1 + b1) -> h1b bf16
  k_gemm<3><<<dim3(32, 32), 256, 0, stream>>>(o1b, W1t, b1, nullptr, h1b, 4096, 4096, 1024, 1.f);

  // 7) FFN2 + residual(out1) -> d_out f32
  k_gemm<8><<<dim3(8, 32), 256, 0, stream>>>(h1b, W2t, b2, o1f, outF, 4096, 1024, 4096, 1.f);

  // 8) LN2 in-place on d_out
  k_layernorm<<<4096, 256, 0, stream>>>(outF, g2, be2, outF, nullptr);
}

// Round 2
// 456.538 us; speedup vs baseline: 1.2375x; 1.2375x over previous
//
#include <hip/hip_runtime.h>

typedef unsigned short u16;
typedef __attribute__((ext_vector_type(8))) short s16x8;
typedef __attribute__((ext_vector_type(4))) float f32x4;

#define MFMA16(a,b,c) __builtin_amdgcn_mfma_f32_16x16x32_bf16((a),(b),(c),0,0,0)
#define LSEQ 2048
#define QSCALE 0.18033688011112042f  /* 0.125 * log2(e) */

__device__ __forceinline__ u16 f2b(float f) {
  union { float f; unsigned u; } v; v.f = f;
  unsigned r = v.u + 0x7FFFu + ((v.u >> 16) & 1u);
  return (u16)(r >> 16);
}
__device__ __forceinline__ u16 f2b_fast(float f) {
  union { float f; unsigned u; } v; v.f = f;
  return (u16)((v.u + 0x8000u) >> 16);
}
__device__ __forceinline__ void g2l16(const void* g, void* l) {
  __builtin_amdgcn_global_load_lds(
      (const __attribute__((address_space(1))) unsigned int*)g,
      (__attribute__((address_space(3))) unsigned int*)l, 16, 0, 0);
}

// ---------------- convert f32 -> bf16, 4 elems/thread ----------------
__global__ __launch_bounds__(256) void k_cvt(const float* __restrict__ in, u16* __restrict__ out, int n) {
  int i = (blockIdx.x * 256 + threadIdx.x) * 4;
  if (i + 3 < n) {
    float4 v = *(const float4*)(in + i);
    ushort4 o;
    o.x = f2b(v.x); o.y = f2b(v.y); o.z = f2b(v.z); o.w = f2b(v.w);
    *(ushort4*)(out + i) = o;
  }
}

// ---------------- bias concat + zero pad region ----------------
__global__ __launch_bounds__(256) void k_prep(const float* __restrict__ bq, const float* __restrict__ bk,
                                              const float* __restrict__ bv, float* __restrict__ bcat,
                                              u16* __restrict__ zeroE) {
  int i = blockIdx.x * 256 + threadIdx.x;
  if (i < 1024) bcat[i] = bq[i];
  else if (i < 2048) bcat[i] = bk[i - 1024];
  else if (i < 3072) bcat[i] = bv[i - 2048];
  if (i < 64) zeroE[i] = 0;
}

// ------------- transpose+convert: W[K,N] f32 -> Wt[N,K] bf16 -------------
__global__ __launch_bounds__(256) void k_transpose(const float* __restrict__ W, u16* __restrict__ Wt, int K, int N) {
  __shared__ float T[64][65];
  int k0 = blockIdx.y * 64, n0 = blockIdx.x * 64;
  int r = threadIdx.x >> 4;
  int c4 = (threadIdx.x & 15) * 4;
#pragma unroll
  for (int i = 0; i < 4; i++) {
    float4 v = *(const float4*)(W + (size_t)(k0 + r + i * 16) * N + n0 + c4);
    T[r + i * 16][c4 + 0] = v.x; T[r + i * 16][c4 + 1] = v.y;
    T[r + i * 16][c4 + 2] = v.z; T[r + i * 16][c4 + 3] = v.w;
  }
  __syncthreads();
#pragma unroll
  for (int i = 0; i < 4; i++) {
    int nl = r + i * 16;
    ushort4 o;
    o.x = f2b(T[c4 + 0][nl]); o.y = f2b(T[c4 + 1][nl]);
    o.z = f2b(T[c4 + 2][nl]); o.w = f2b(T[c4 + 3][nl]);
    *(ushort4*)(Wt + (size_t)(n0 + nl) * K + k0 + c4) = o;
  }
}

// ------------- bf16 MFMA GEMM, gload_lds dbuf, swizzled LDS -------------
// C[M,N] = A[M,K] @ Bt[N,K]^T + bias.  FLAGS: 1=RELU, 2=BF16OUT, 4=QKV, 8=RESID(f32 out)
template <int BN, int FLAGS>
__global__ __launch_bounds__(256) void k_gemm(const u16* __restrict__ A, const u16* __restrict__ Bt,
                                              const float* __restrict__ bias, const float* __restrict__ resid,
                                              void* __restrict__ Cout, int M, int N, int K) {
  constexpr int MI = (BN == 128) ? 4 : 2;
  __shared__ __align__(16) u16 As[2][128 * 32];
  __shared__ __align__(16) u16 Bs[2][BN * 32];
  const int tid = threadIdx.x;
  const int lane = tid & 63, wave = tid >> 6;
  const int lo = lane & 15, hi = lane >> 4;
  const int WROW = (BN == 128) ? (wave >> 1) * 64 : wave * 32;
  const int WCOL = (BN == 128) ? (wave & 1) * 64 : 0;
  const int m0 = blockIdx.y * 128, n0 = blockIdx.x * BN;

  const int colg = ((lane & 3) * 16) ^ (((lane >> 3) & 3) << 4);  // staging src col (pre-swizzled)
  const int arow = wave * 32 + (lane >> 2);
  const int swzr = ((lane >> 1) & 3) << 4;                        // read-side swizzle

  f32x4 acc[MI][4];
#pragma unroll
  for (int mi = 0; mi < MI; mi++)
#pragma unroll
    for (int ni = 0; ni < 4; ni++) acc[mi][ni] = (f32x4){0.f, 0.f, 0.f, 0.f};

  const char* Ab = (const char*)A;
  const char* Bb = (const char*)Bt;
  const int nt = K >> 5;

  auto stage = [&](int buf, int t) {
    const int k0 = t * 32;
    char* ad = (char*)&As[buf][0] + wave * 2048;
    const char* as = Ab + ((size_t)(m0 + arow) * K + k0) * 2 + colg;
    g2l16(as, ad);
    g2l16(as + (size_t)16 * K * 2, ad + 1024);
    if (BN == 128) {
      char* bd = (char*)&Bs[buf][0] + wave * 2048;
      const char* bs = Bb + ((size_t)(n0 + arow) * K + k0) * 2 + colg;
      g2l16(bs, bd);
      g2l16(bs + (size_t)16 * K * 2, bd + 1024);
    } else {
      char* bd = (char*)&Bs[buf][0] + wave * 1024;
      const int brow = wave * 16 + (lane >> 2);
      const char* bs = Bb + ((size_t)(n0 + brow) * K + k0) * 2 + colg;
      g2l16(bs, bd);
    }
  };

  stage(0, 0);
  int buf = 0;
  for (int t = 0; t < nt; t++) {
    __syncthreads();   // staged buf ready (vmcnt drained by barrier)
    if (t + 1 < nt) stage(buf ^ 1, t + 1);
    const char* ab = (const char*)&As[buf][0];
    const char* bb2 = (const char*)&Bs[buf][0];
    s16x8 af[MI], bfr[4];
#pragma unroll
    for (int mi = 0; mi < MI; mi++) {
      int row = WROW + mi * 16 + lo;
      af[mi] = *(const s16x8*)(ab + row * 64 + ((hi * 16) ^ swzr));
    }
#pragma unroll
    for (int ni = 0; ni < 4; ni++) {
      int row = WCOL + ni * 16 + lo;
      bfr[ni] = *(const s16x8*)(bb2 + row * 64 + ((hi * 16) ^ swzr));
    }
#pragma unroll
    for (int mi = 0; mi < MI; mi++)
#pragma unroll
      for (int ni = 0; ni < 4; ni++)
        acc[mi][ni] = MFMA16(af[mi], bfr[ni], acc[mi][ni]);
    buf ^= 1;
  }

#pragma unroll
  for (int mi = 0; mi < MI; mi++)
#pragma unroll
    for (int ni = 0; ni < 4; ni++) {
      const int mb = m0 + WROW + mi * 16 + hi * 4;
      const int n = n0 + WCOL + ni * 16 + lo;
      float v4[4];
#pragma unroll
      for (int reg = 0; reg < 4; reg++) {
        float v = acc[mi][ni][reg] + bias[n];
        if (FLAGS & 8) v += resid[(size_t)(mb + reg) * N + n];
        if (FLAGS & 1) v = fmaxf(v, 0.f);
        v4[reg] = v;
      }
      if (FLAGS & 4) {
        const int seg = n >> 10, nn = n & 1023;
        const int hh = nn >> 6, dd = nn & 63;
        const int bb = mb >> 11, ll = mb & 2047;
        u16* dst = (u16*)Cout + (size_t)seg * 4194304;
        if (seg == 0) {
#pragma unroll
          for (int reg = 0; reg < 4; reg++)
            dst[((size_t)(bb * 16 + hh) * LSEQ + ll + reg) * 64 + dd] = f2b(v4[reg] * QSCALE);
        } else if (seg == 1) {
#pragma unroll
          for (int reg = 0; reg < 4; reg++)
            dst[((size_t)(bb * 16 + hh) * LSEQ + ll + reg) * 64 + dd] = f2b(v4[reg]);
        } else {
          ushort4 o;
          o.x = f2b(v4[0]); o.y = f2b(v4[1]); o.z = f2b(v4[2]); o.w = f2b(v4[3]);
          *(ushort4*)&((u16*)dst)[((size_t)(bb * 16 + hh) * 64 + dd) * LSEQ + ll] = o;
        }
      } else if (FLAGS & 2) {
        u16* dst = (u16*)Cout;
#pragma unroll
        for (int reg = 0; reg < 4; reg++) dst[(size_t)(mb + reg) * N + n] = f2b(v4[reg]);
      } else {
        float* dst = (float*)Cout;
#pragma unroll
        for (int reg = 0; reg < 4; reg++) dst[(size_t)(mb + reg) * N + n] = v4[reg];
      }
    }
}

// ------------- fused rel-pos flash attention (exp2 domain, Q pre-scaled) -------------
// Qh/Kh = [B*H, L, 64] bf16; Vt = [B*H, 64, L] bf16; Ob = [B*L, 1024] bf16.
__global__ __launch_bounds__(256) void k_attn(const u16* __restrict__ Qh, const u16* __restrict__ Kh,
                                              const u16* __restrict__ Vt, const u16* __restrict__ Eb,
                                              const u16* __restrict__ Zb, u16* __restrict__ Ob) {
  __shared__ __align__(16) u16 Ksh[64 * 64];    // [j][dh] swizzled
  __shared__ __align__(16) u16 Vts[64 * 64];    // [dh][j] swizzled
  __shared__ __align__(16) u16 Esh[128 * 64];   // [band][dh] swizzled
  __shared__ __align__(16) float GP[4][16 * 84];  // per-wave union: G f32 [16][84] / P u16 [16][68]

  const int tid = threadIdx.x;
  const int lane = tid & 63, wave = tid >> 6;
  const int lo = lane & 15, hi = lane >> 4;
  const int l0 = blockIdx.x * 64;
  const int bh = blockIdx.y;
  const int bb = bh >> 4, hh = bh & 15;
  const int lw = l0 + wave * 16;

  const char* Kb = (const char*)(Kh + (size_t)bh * LSEQ * 64);
  const char* Vb = (const char*)(Vt + (size_t)bh * 64 * LSEQ);
  const u16* Qbase = Qh + (size_t)bh * LSEQ * 64;

  const int colsw = ((lane & 7) * 16) ^ (((lane >> 3) & 7) << 4);  // staging src col
  const int c0 = (hi * 16) ^ ((lane & 7) << 4);                    // read col (swizzled)

  auto stageKV = [&](int j0) {
#pragma unroll
    for (int i = 0; i < 2; i++) {
      char* kd = (char*)Ksh + wave * 2048 + i * 1024;
      const char* ks = Kb + (size_t)(j0 + wave * 16 + i * 8 + (lane >> 3)) * 128 + colsw;
      g2l16(ks, kd);
      char* vd = (char*)Vts + wave * 2048 + i * 1024;
      const char* vs = Vb + (size_t)(wave * 16 + i * 8 + (lane >> 3)) * (LSEQ * 2) + (size_t)j0 * 2 + colsw;
      g2l16(vs, vd);
    }
  };
  auto stageE = [&](int j0) {
    const int mbB = LSEQ - 64 - l0 + j0;
#pragma unroll
    for (int i = 0; i < 4; i++) {
      char* ed = (char*)Esh + wave * 4096 + i * 1024;
      int mrow = mbB + wave * 32 + i * 8 + (lane >> 3);
      const char* es = (mrow < LSEQ) ? ((const char*)Eb + (size_t)mrow * 128 + colsw)
                                     : ((const char*)Zb + colsw);
      g2l16(es, ed);
    }
  };

  s16x8 aq[2];
  aq[0] = *(const s16x8*)(Qbase + (size_t)(lw + lo) * 64 + hi * 8);
  aq[1] = *(const s16x8*)(Qbase + (size_t)(lw + lo) * 64 + 32 + hi * 8);

  float m_run[4], l_run[4];
  f32x4 oacc[4];
#pragma unroll
  for (int r = 0; r < 4; r++) { m_run[r] = -1e30f; l_run[r] = 0.f; }
#pragma unroll
  for (int f = 0; f < 4; f++) oacc[f] = (f32x4){0.f, 0.f, 0.f, 0.f};

  float* gp = &GP[wave][0];
  u16* pp = (u16*)gp;

  stageKV(0);
  stageE(0);

  for (int t = 0; t < 32; t++) {
    const int j0 = t * 64;
    const bool has_rel = (j0 <= l0);
    __syncthreads();

    // S = Q K^T (log2 domain via pre-scaled Q)
    f32x4 s4[4];
#pragma unroll
    for (int c = 0; c < 4; c++) {
      const char* kb2 = (const char*)Ksh + (c * 16 + lo) * 128;
      s16x8 b0 = *(const s16x8*)(kb2 + c0);
      s16x8 b1 = *(const s16x8*)(kb2 + (c0 ^ 64));
      s4[c] = (f32x4){0.f, 0.f, 0.f, 0.f};
      s4[c] = MFMA16(aq[0], b0, s4[c]);
      s4[c] = MFMA16(aq[1], b1, s4[c]);
    }

    if (has_rel) {
      const int offW = 48 - 16 * wave;
#pragma unroll
      for (int c2 = 0; c2 < 5; c2++) {
        const char* ebp = (const char*)Esh + (offW + c2 * 16 + lo) * 128;
        s16x8 e0 = *(const s16x8*)(ebp + c0);
        s16x8 e1 = *(const s16x8*)(ebp + (c0 ^ 64));
        f32x4 g = (f32x4){0.f, 0.f, 0.f, 0.f};
        g = MFMA16(aq[0], e0, g);
        g = MFMA16(aq[1], e1, g);
#pragma unroll
        for (int reg = 0; reg < 4; reg++) gp[(hi * 4 + reg) * 84 + c2 * 16 + lo] = g[reg];
      }
#pragma unroll
      for (int c = 0; c < 4; c++)
#pragma unroll
        for (int reg = 0; reg < 4; reg++) {
          int r = hi * 4 + reg;
          int jg = j0 + c * 16 + lo;
          int lg = lw + r;
          if (jg <= lg) s4[c][reg] += gp[r * 84 + 15 - r + c * 16 + lo];
        }
    }

    // online softmax (base-2)
    float mt[4];
#pragma unroll
    for (int reg = 0; reg < 4; reg++)
      mt[reg] = fmaxf(fmaxf(s4[0][reg], s4[1][reg]), fmaxf(s4[2][reg], s4[3][reg]));
#pragma unroll
    for (int msk = 1; msk <= 8; msk <<= 1)
#pragma unroll
      for (int reg = 0; reg < 4; reg++)
        mt[reg] = fmaxf(mt[reg], __shfl_xor(mt[reg], msk, 64));
    float psum[4];
#pragma unroll
    for (int reg = 0; reg < 4; reg++) {
      float mnew = fmaxf(m_run[reg], mt[reg]);
      float scl = exp2f(m_run[reg] - mnew);
      m_run[reg] = mnew;
      l_run[reg] *= scl;
#pragma unroll
      for (int f = 0; f < 4; f++) oacc[f][reg] *= scl;
      psum[reg] = 0.f;
    }
#pragma unroll
    for (int c = 0; c < 4; c++)
#pragma unroll
      for (int reg = 0; reg < 4; reg++) {
        float p = exp2f(s4[c][reg] - m_run[reg]);
        psum[reg] += p;
        pp[(hi * 4 + reg) * 68 + c * 16 + lo] = f2b_fast(p);
      }
#pragma unroll
    for (int msk = 1; msk <= 8; msk <<= 1)
#pragma unroll
      for (int reg = 0; reg < 4; reg++)
        psum[reg] += __shfl_xor(psum[reg], msk, 64);
#pragma unroll
    for (int reg = 0; reg < 4; reg++) l_run[reg] += psum[reg];

    // O += P V
    s16x8 pa0 = *(const s16x8*)(pp + lo * 68 + hi * 8);
    s16x8 pa1 = *(const s16x8*)(pp + lo * 68 + 32 + hi * 8);
#pragma unroll
    for (int f = 0; f < 4; f++) {
      const char* vbp = (const char*)Vts + (f * 16 + lo) * 128;
      s16x8 v0 = *(const s16x8*)(vbp + c0);
      s16x8 v1 = *(const s16x8*)(vbp + (c0 ^ 64));
      oacc[f] = MFMA16(pa0, v0, oacc[f]);
      oacc[f] = MFMA16(pa1, v1, oacc[f]);
    }

    __syncthreads();
    if (t < 31) {
      stageKV(j0 + 64);
      if (j0 + 64 <= l0) stageE(j0 + 64);
    }
  }

  float inv[4];
#pragma unroll
  for (int reg = 0; reg < 4; reg++) inv[reg] = 1.f / l_run[reg];
#pragma unroll
  for (int f = 0; f < 4; f++)
#pragma unroll
    for (int reg = 0; reg < 4; reg++) {
      float o = oacc[f][reg] * inv[reg];
      size_t idx = (size_t)(bb * LSEQ + lw + hi * 4 + reg) * 1024 + hh * 64 + f * 16 + lo;
      Ob[idx] = f2b(o);
    }
}

// ------------- LayerNorm over rows of 1024, optional bf16 copy -------------
__global__ __launch_bounds__(256) void k_layernorm(const float* __restrict__ X, const float* __restrict__ gw,
                                                   const float* __restrict__ bw, float* __restrict__ outF,
                                                   u16* __restrict__ outB) {
  __shared__ float red[2][4];
  const int row = blockIdx.x, tid = threadIdx.x;
  const int lane = tid & 63, wave = tid >> 6;
  const float* x = X + (size_t)row * 1024;
  float4 v = *(const float4*)(x + tid * 4);
  float s = v.x + v.y + v.z + v.w;
  float s2 = v.x * v.x + v.y * v.y + v.z * v.z + v.w * v.w;
#pragma unroll
  for (int msk = 1; msk <= 32; msk <<= 1) {
    s += __shfl_xor(s, msk, 64);
    s2 += __shfl_xor(s2, msk, 64);
  }
  if (lane == 0) { red[0][wave] = s; red[1][wave] = s2; }
  __syncthreads();
  s = red[0][0] + red[0][1] + red[0][2] + red[0][3];
  s2 = red[1][0] + red[1][1] + red[1][2] + red[1][3];
  float mean = s * (1.f / 1024.f);
  float var = s2 * (1.f / 1024.f) - mean * mean;
  float rs = rsqrtf(var + 1e-6f);
  float4 g4 = *(const float4*)(gw + tid * 4);
  float4 b4 = *(const float4*)(bw + tid * 4);
  float4 o;
  o.x = (v.x - mean) * rs * g4.x + b4.x;
  o.y = (v.y - mean) * rs * g4.y + b4.y;
  o.z = (v.z - mean) * rs * g4.z + b4.z;
  o.w = (v.w - mean) * rs * g4.w + b4.w;
  *(float4*)(outF + (size_t)row * 1024 + tid * 4) = o;
  if (outB) {
    ushort4 ob;
    ob.x = f2b(o.x); ob.y = f2b(o.y); ob.z = f2b(o.z); ob.w = f2b(o.w);
    *(ushort4*)(outB + (size_t)row * 1024 + tid * 4) = ob;
  }
}

extern "C" void kernel_launch(void* const* d_in, const int* in_sizes, int n_in,
                              void* d_out, int out_size, void* d_ws, size_t ws_size,
                              hipStream_t stream) {
  const float* x   = (const float*)d_in[0];
  const float* Wq  = (const float*)d_in[1];
  const float* bq  = (const float*)d_in[2];
  const float* Wk  = (const float*)d_in[3];
  const float* bk  = (const float*)d_in[4];
  const float* Wv  = (const float*)d_in[5];
  const float* bv  = (const float*)d_in[6];
  const float* Wo  = (const float*)d_in[7];
  const float* bo  = (const float*)d_in[8];
  const float* E   = (const float*)d_in[9];
  const float* W1  = (const float*)d_in[10];
  const float* b1  = (const float*)d_in[11];
  const float* W2  = (const float*)d_in[12];
  const float* b2  = (const float*)d_in[13];
  const float* g1  = (const float*)d_in[14];
  const float* be1 = (const float*)d_in[15];
  const float* g2  = (const float*)d_in[16];
  const float* be2 = (const float*)d_in[17];

  char* ws = (char*)d_ws;
  const size_t MB = 1ull << 20;
  u16* Wqt = (u16*)(ws + 0 * MB);          // 6MB contiguous [3072][1024] (Wq/Wk/Wv)
  u16* Wkt = (u16*)(ws + 2 * MB);
  u16* Wvt = (u16*)(ws + 4 * MB);
  u16* Wot = (u16*)(ws + 6 * MB);          // 2MB
  u16* W1t = (u16*)(ws + 8 * MB);          // 8MB [4096][1024]
  u16* W2t = (u16*)(ws + 16 * MB);         // 8MB [1024][4096]
  u16* Ebf = (u16*)(ws + 24 * MB);         // 256KB [2048][64]
  float* bcat = (float*)(ws + 24 * MB + 256 * 1024);  // 12KB
  u16* zeroE = (u16*)(ws + 24 * MB + 384 * 1024);     // 128B
  u16* xb  = (u16*)(ws + 25 * MB);         // 8MB [4096][1024]
  u16* qb  = (u16*)(ws + 33 * MB);         // 8MB head-major (QSCALE'd)
  u16* kb  = (u16*)(ws + 41 * MB);         // 8MB head-major
  u16* vt  = (u16*)(ws + 49 * MB);         // 8MB transposed [bh][64][L]
  u16* ao  = (u16*)(ws + 57 * MB);         // 8MB [4096][1024]
  float* t1 = (float*)(ws + 65 * MB);      // 16MB f32
  u16* o1b  = (u16*)(ws + 25 * MB);        // reuse xb
  float* o1f = (float*)(ws + 33 * MB);     // reuse qb/kb
  u16* h1b  = (u16*)(ws + 49 * MB);        // reuse vt/ao/t1, 32MB [4096][4096]
  float* outF = (float*)d_out;

  // 1) conversions / prep
  k_cvt<<<4096, 256, 0, stream>>>(x, xb, 4096 * 1024);
  k_cvt<<<128, 256, 0, stream>>>(E, Ebf, 2048 * 64);
  k_prep<<<12, 256, 0, stream>>>(bq, bk, bv, bcat, zeroE);
  k_transpose<<<dim3(16, 16), 256, 0, stream>>>(Wq, Wqt, 1024, 1024);
  k_transpose<<<dim3(16, 16), 256, 0, stream>>>(Wk, Wkt, 1024, 1024);
  k_transpose<<<dim3(16, 16), 256, 0, stream>>>(Wv, Wvt, 1024, 1024);
  k_transpose<<<dim3(16, 16), 256, 0, stream>>>(Wo, Wot, 1024, 1024);
  k_transpose<<<dim3(64, 16), 256, 0, stream>>>(W1, W1t, 1024, 4096);
  k_transpose<<<dim3(16, 64), 256, 0, stream>>>(W2, W2t, 4096, 1024);

  // 2) fused QKV projection (writes qb, kb, vt)
  k_gemm<128, 4><<<dim3(24, 32), 256, 0, stream>>>(xb, Wqt, bcat, nullptr, qb, 4096, 3072, 1024);

  // 3) rel-pos flash attention -> ao
  k_attn<<<dim3(32, 32), 256, 0, stream>>>(qb, kb, vt, Ebf, zeroE, ao);

  // 4) O-proj + residual(x) -> t1 f32
  k_gemm<64, 8><<<dim3(16, 32), 256, 0, stream>>>(ao, Wot, bo, x, t1, 4096, 1024, 1024);

  // 5) LN1 -> o1f (f32) + o1b (bf16)
  k_layernorm<<<4096, 256, 0, stream>>>(t1, g1, be1, o1f, o1b);

  // 6) FFN1: relu(out1 @ W1 + b1) -> h1b bf16
  k_gemm<128, 3><<<dim3(32, 32), 256, 0, stream>>>(o1b, W1t, b1, nullptr, h1b, 4096, 4096, 1024);

  // 7) FFN2 + residual(o1f) -> d_out f32
  k_gemm<64, 8><<<dim3(16, 32), 256, 0, stream>>>(h1b, W2t, b2, o1f, outF, 4096, 1024, 4096);

  // 8) LN2 in-place on d_out
  k_layernorm<<<4096, 256, 0, stream>>>(outF, g2, be2, outF, nullptr);
}